// Round 1
// baseline (638.053 us; speedup 1.0000x reference)
//
#include <hip/hip_runtime.h>
#include <hip/hip_bf16.h>

#define H 128
#define TILE_M 64
#define KC 32
#define EPB 64

__device__ __forceinline__ float silu_f(float v) {
    return v / (1.0f + __expf(-v));
}

// Fused two-layer dense: y = silu(silu(x@w0+b0)@w1+b1) [+ res]
// M must be a multiple of TILE_M (40000 = 625*64).
template <bool RESID>
__global__ __launch_bounds__(256)
void mlp2_kernel(const float* __restrict__ x,
                 const float* __restrict__ w0, const float* __restrict__ b0,
                 const float* __restrict__ w1, const float* __restrict__ b1,
                 const float* __restrict__ res,
                 float* __restrict__ y, int M)
{
    __shared__ float xs[TILE_M][H + 4];   // padded: 64x132 = 33.8 KB
    __shared__ float ws[KC][H];           // 16 KB

    const int tid  = threadIdx.x;
    const int row0 = blockIdx.x * TILE_M;
    const int cg   = (tid & 31) * 4;      // 4-col group
    const int rg   = tid >> 5;            // 8-row group (rows rg*8..rg*8+7)

    // stage x tile (64x128), 8 float4 per thread, coalesced
#pragma unroll
    for (int i = 0; i < 8; ++i) {
        int flat = tid * 4 + i * 1024;
        int r = flat >> 7, c = flat & 127;
        *(float4*)&xs[r][c] = *(const float4*)(x + (size_t)(row0 + r) * H + c);
    }

    const float* w = w0;
    const float* bb = b0;
    float4 acc[8];

#pragma unroll
    for (int layer = 0; layer < 2; ++layer) {
#pragma unroll
        for (int i = 0; i < 8; ++i) acc[i] = make_float4(0.f, 0.f, 0.f, 0.f);

        for (int kc = 0; kc < H; kc += KC) {
            __syncthreads();              // protect ws (and xs writes from prev layer)
            // stage weight chunk (32x128)
#pragma unroll
            for (int i = 0; i < 4; ++i) {
                int flat = tid * 4 + i * 1024;
                int kk = flat >> 7, c = flat & 127;
                *(float4*)&ws[kk][c] = *(const float4*)(w + (size_t)(kc + kk) * H + c);
            }
            __syncthreads();
#pragma unroll 4
            for (int k = 0; k < KC; ++k) {
                float4 wv = *(float4*)&ws[k][cg];
#pragma unroll
                for (int i = 0; i < 8; ++i) {
                    float xv = xs[rg * 8 + i][kc + k];
                    acc[i].x = fmaf(xv, wv.x, acc[i].x);
                    acc[i].y = fmaf(xv, wv.y, acc[i].y);
                    acc[i].z = fmaf(xv, wv.z, acc[i].z);
                    acc[i].w = fmaf(xv, wv.w, acc[i].w);
                }
            }
        }

        float4 bv = *(const float4*)(bb + cg);
        __syncthreads();                  // all xs reads done before overwrite
#pragma unroll
        for (int i = 0; i < 8; ++i) {
            int r = rg * 8 + i;
            float4 v;
            v.x = silu_f(acc[i].x + bv.x);
            v.y = silu_f(acc[i].y + bv.y);
            v.z = silu_f(acc[i].z + bv.z);
            v.w = silu_f(acc[i].w + bv.w);
            if (layer == 0) {
                *(float4*)&xs[r][cg] = v;     // hidden stays in LDS
            } else {
                if (RESID) {
                    float4 rv = *(const float4*)(res + (size_t)(row0 + r) * H + cg);
                    v.x += rv.x; v.y += rv.y; v.z += rv.z; v.w += rv.w;
                }
                *(float4*)(y + (size_t)(row0 + r) * H + cg) = v;
            }
        }
        w = w1; bb = b1;
    }
}

// Fused: proj = ef@e_w (per edge), val = scalar_dst[col]*proj*C[b],
// atomic scatter-add into conv[row]. EPB edges per block; E % EPB == 0 so a
// block never crosses a batch boundary.
__global__ __launch_bounds__(256)
void edge_kernel(const float* __restrict__ ef,    // [B,E,32]
                 const int*   __restrict__ eidx,  // [B,E,2]
                 const float* __restrict__ sdst,  // [B,N,H]
                 const float* __restrict__ ew,    // [32,H]
                 const float* __restrict__ C,     // [B]
                 float* __restrict__ conv,        // [B,N,H]
                 int E, int N)
{
    __shared__ float ews[32][H];          // 16 KB
    __shared__ float efs[EPB][33];        // padded
    __shared__ int   rcs[EPB][2];

    const int tid = threadIdx.x;
    const int g0  = blockIdx.x * EPB;     // flat edge id base (fits int)
    const int b   = g0 / E;
    const float Cb = C[b];

    // stage e_w (32x128)
#pragma unroll
    for (int i = 0; i < 4; ++i) {
        int flat = tid * 4 + i * 1024;
        *(float4*)&ews[flat >> 7][flat & 127] = *(const float4*)(ew + flat);
    }
    // stage ef for EPB edges (64x32)
#pragma unroll
    for (int i = 0; i < 8; ++i) {
        int flat = tid + i * 256;
        efs[flat >> 5][flat & 31] = ef[(size_t)(g0 + (flat >> 5)) * 32 + (flat & 31)];
    }
    // stage row/col
    if (tid < EPB * 2) {
        rcs[tid >> 1][tid & 1] = eidx[(size_t)g0 * 2 + tid];
    }
    __syncthreads();

    const int h   = tid & 127;
    const int sub = tid >> 7;             // 0..1, two edges in flight per block pass
    for (int el = sub; el < EPB; el += 2) {
        int row = rcs[el][0];
        int col = rcs[el][1];
        float proj = 0.f;
#pragma unroll
        for (int k = 0; k < 32; ++k)
            proj = fmaf(efs[el][k], ews[k][h], proj);
        float v = sdst[((size_t)b * N + col) * H + h] * proj * Cb;
        atomicAdd(&conv[((size_t)b * N + row) * H + h], v);
    }
}

__global__ __launch_bounds__(256)
void mul_kernel(const float* __restrict__ a, const float* __restrict__ bvec,
                float* __restrict__ o, int n4)
{
    int i = blockIdx.x * blockDim.x + threadIdx.x;
    if (i < n4) {
        float4 av = ((const float4*)a)[i];
        float4 bv = ((const float4*)bvec)[i];
        float4 ov;
        ov.x = av.x * bv.x; ov.y = av.y * bv.y;
        ov.z = av.z * bv.z; ov.w = av.w * bv.w;
        ((float4*)o)[i] = ov;
    }
}

extern "C" void kernel_launch(void* const* d_in, const int* in_sizes, int n_in,
                              void* d_out, int out_size, void* d_ws, size_t ws_size,
                              hipStream_t stream)
{
    const float* scalar = (const float*)d_in[0];   // [B,N,H]
    const float* ef     = (const float*)d_in[1];   // [B,E,32]
    const int*   eidx   = (const int*)d_in[2];     // [B,E,2]
    const float* C      = (const float*)d_in[3];   // [B]
    const float* emb_w  = (const float*)d_in[4];   // [2,2,H,H]
    const float* emb_b  = (const float*)d_in[5];   // [2,2,H]
    const float* e_w    = (const float*)d_in[6];   // [32,H]
    const float* conv_w = (const float*)d_in[7];   // [2,2,H,H]
    const float* conv_b = (const float*)d_in[8];   // [2,2,H]
    const float* out_w  = (const float*)d_in[9];   // [2,H,H]
    const float* out_b  = (const float*)d_in[10];  // [2,H]

    const int B = 4, N = 10000, E = 160000;
    const int M = B * N;                           // 40000
    const size_t nodeElems = (size_t)M * H;        // 5.12M floats

    float* s2s  = (float*)d_ws;
    float* sdst = s2s  + nodeElems;                // later reused as z = s2s*conv
    float* conv = sdst + nodeElems;

    const int HH = H * H;
    dim3 blk(256);
    dim3 grid_mlp(M / TILE_M);                     // 625
    dim3 grid_edge((B * E) / EPB);                 // 10000
    dim3 grid_mul((int)((nodeElems / 4 + 255) / 256));

    hipMemsetAsync(conv, 0, nodeElems * sizeof(float), stream);

    // s2s = Dense(Dense(scalar; emb[0,0]); emb[0,1])
    mlp2_kernel<false><<<grid_mlp, blk, 0, stream>>>(
        scalar, emb_w, emb_b, emb_w + HH, emb_b + H, nullptr, s2s, M);
    // scalar_dst = Dense(Dense(scalar; emb[1,0]); emb[1,1])
    mlp2_kernel<false><<<grid_mlp, blk, 0, stream>>>(
        scalar, emb_w + 2 * HH, emb_b + 2 * H, emb_w + 3 * HH, emb_b + 3 * H,
        nullptr, sdst, M);
    // conv = segment_sum(gather(sdst,col)*ef@e_w, row) * C   (C folded in)
    edge_kernel<<<grid_edge, blk, 0, stream>>>(ef, eidx, sdst, e_w, C, conv, E, N);
    // conv = residual(conv; conv_w[0])
    mlp2_kernel<true><<<grid_mlp, blk, 0, stream>>>(
        conv, conv_w, conv_b, conv_w + HH, conv_b + H, conv, conv, M);
    // conv = residual(conv; conv_w[1])
    mlp2_kernel<true><<<grid_mlp, blk, 0, stream>>>(
        conv, conv_w + 2 * HH, conv_b + 2 * H, conv_w + 3 * HH, conv_b + 3 * H,
        conv, conv, M);
    // z = s2s * conv   (reuse sdst buffer)
    mul_kernel<<<grid_mul, blk, 0, stream>>>(s2s, conv, sdst, (int)(nodeElems / 4));
    // out = residual(z; out_w)
    mlp2_kernel<true><<<grid_mlp, blk, 0, stream>>>(
        sdst, out_w, out_b, out_w + HH, out_b + H, sdst, (float*)d_out, M);
}

// Round 2
// 495.661 us; speedup vs baseline: 1.2873x; 1.2873x over previous
//
#include <hip/hip_runtime.h>
#include <hip/hip_bf16.h>

#define H 128
#define TILE_M 64
#define EPB 64
#define SX 132   // LDS stride (halves) for x tile: 8B-aligned, banks spread (66 words)

typedef _Float16 f16x4 __attribute__((ext_vector_type(4)));
typedef _Float16 f16x8 __attribute__((ext_vector_type(8)));
typedef float    f32x4 __attribute__((ext_vector_type(4)));

__device__ __forceinline__ float silu_f(float v) {
    return v / (1.0f + __expf(-v));
}

__device__ __forceinline__ f16x8 ld_frag(const _Float16* p) {
    // two 8B loads: per-lane addr is only guaranteed 8B-aligned (stride 132 halves)
    f16x4 lo = *(const f16x4*)p;
    f16x4 hi = *(const f16x4*)(p + 4);
    f16x8 r;
    r[0] = lo[0]; r[1] = lo[1]; r[2] = lo[2]; r[3] = lo[3];
    r[4] = hi[0]; r[5] = hi[1]; r[6] = hi[2]; r[7] = hi[3];
    return r;
}

// Stage w (f32 [128k][128c] row-major) transposed into LDS as fp16 wt[c][k],
// stride SX halves. Global reads coalesced (lanes = consecutive c, same k).
__device__ __forceinline__ void stage_wt(const float* __restrict__ wf,
                                         _Float16* wt, int tid) {
    const int c  = tid & 127;
    const int kh = (tid >> 7) * 4;            // 0 or 4
#pragma unroll 4
    for (int kk = 0; kk < 16; ++kk) {
        int k0 = kk * 8 + kh;
        float a0 = wf[(k0 + 0) * H + c];
        float a1 = wf[(k0 + 1) * H + c];
        float a2 = wf[(k0 + 2) * H + c];
        float a3 = wf[(k0 + 3) * H + c];
        f16x4 hv = {(_Float16)a0, (_Float16)a1, (_Float16)a2, (_Float16)a3};
        *(f16x4*)&wt[c * SX + k0] = hv;
    }
}

// Fused two-layer dense on matrix cores (fp16 in, fp32 accum):
//   MODE 0: y = mlp2(x)
//   MODE 1: y = x + mlp2(x)                  (residual)
//   MODE 2: z = x .* x2;  y = z + mlp2(z)    (fused mul + residual)
// Wave w computes rows [wid*16, wid*16+16) x all 128 cols of its block tile.
// MFMA mapping: A = w^T frag (m = out-col), B = x frag (n = row);
// D: lane holds row = r0 + (lane&15), cols c0 + quad*4 + [0..3]  -> float4 store.
template <int MODE>
__global__ __launch_bounds__(256)
void mlp2_mfma(const float* __restrict__ x, const float* __restrict__ x2,
               const float* __restrict__ w0f, const float* __restrict__ b0,
               const float* __restrict__ w1f, const float* __restrict__ b1,
               float* __restrict__ y, int M)
{
    __shared__ _Float16 xs[TILE_M * SX];   // 16.9 KB
    __shared__ _Float16 wt[H * SX];        // 33.8 KB

    const int tid  = threadIdx.x;
    const int row0 = blockIdx.x * TILE_M;
    const int lane = tid & 63;
    const int wid  = tid >> 6;
    const int rl   = lane & 15;            // n: row within wave's 16-row strip
    const int quad = lane >> 4;            // k-quad / out-col quad
    const int rowl = wid * 16 + rl;        // block-local row this lane owns in D

    // ---- stage x tile (64x128 f32 -> fp16), coalesced float4 reads ----
#pragma unroll
    for (int i = 0; i < 8; ++i) {
        int flat = tid * 4 + i * 1024;
        int r = flat >> 7, c = flat & 127;
        float4 v = *(const float4*)(x + (size_t)(row0 + r) * H + c);
        if (MODE == 2) {
            float4 u = *(const float4*)(x2 + (size_t)(row0 + r) * H + c);
            v.x *= u.x; v.y *= u.y; v.z *= u.z; v.w *= u.w;
        }
        f16x4 hv = {(_Float16)v.x, (_Float16)v.y, (_Float16)v.z, (_Float16)v.w};
        *(f16x4*)&xs[r * SX + c] = hv;
    }
    stage_wt(w0f, wt, tid);
    __syncthreads();

    f32x4 acc[8];

    // ================= layer 1 =================
#pragma unroll
    for (int ct = 0; ct < 8; ++ct) acc[ct] = (f32x4){0.f, 0.f, 0.f, 0.f};
#pragma unroll
    for (int kc = 0; kc < H; kc += 32) {
        f16x8 bf = ld_frag(&xs[rowl * SX + kc + quad * 8]);
#pragma unroll
        for (int ct = 0; ct < 8; ++ct) {
            f16x8 af = ld_frag(&wt[(ct * 16 + rl) * SX + kc + quad * 8]);
            acc[ct] = __builtin_amdgcn_mfma_f32_16x16x32_f16(af, bf, acc[ct], 0, 0, 0);
        }
    }
    __syncthreads();   // all wt/xs reads done before overwrite

    // hidden = silu(acc + b0) -> back into xs (fp16), wave-local rows
#pragma unroll
    for (int ct = 0; ct < 8; ++ct) {
        int c = ct * 16 + quad * 4;
        float4 bb = *(const float4*)(b0 + c);
        f16x4 hv = {(_Float16)silu_f(acc[ct][0] + bb.x),
                    (_Float16)silu_f(acc[ct][1] + bb.y),
                    (_Float16)silu_f(acc[ct][2] + bb.z),
                    (_Float16)silu_f(acc[ct][3] + bb.w)};
        *(f16x4*)&xs[rowl * SX + c] = hv;
    }
    stage_wt(w1f, wt, tid);
    __syncthreads();

    // ================= layer 2 =================
#pragma unroll
    for (int ct = 0; ct < 8; ++ct) acc[ct] = (f32x4){0.f, 0.f, 0.f, 0.f};
#pragma unroll
    for (int kc = 0; kc < H; kc += 32) {
        f16x8 bf = ld_frag(&xs[rowl * SX + kc + quad * 8]);
#pragma unroll
        for (int ct = 0; ct < 8; ++ct) {
            f16x8 af = ld_frag(&wt[(ct * 16 + rl) * SX + kc + quad * 8]);
            acc[ct] = __builtin_amdgcn_mfma_f32_16x16x32_f16(af, bf, acc[ct], 0, 0, 0);
        }
    }

    // epilogue: y = silu(acc + b1) [+ residual]
    const size_t rbase = (size_t)(row0 + rowl) * H;
#pragma unroll
    for (int ct = 0; ct < 8; ++ct) {
        int c = ct * 16 + quad * 4;
        float4 bb = *(const float4*)(b1 + c);
        float4 v;
        v.x = silu_f(acc[ct][0] + bb.x);
        v.y = silu_f(acc[ct][1] + bb.y);
        v.z = silu_f(acc[ct][2] + bb.z);
        v.w = silu_f(acc[ct][3] + bb.w);
        if (MODE == 1) {
            float4 rv = *(const float4*)(x + rbase + c);
            v.x += rv.x; v.y += rv.y; v.z += rv.z; v.w += rv.w;
        } else if (MODE == 2) {
            float4 ra = *(const float4*)(x  + rbase + c);
            float4 rb = *(const float4*)(x2 + rbase + c);
            v.x += ra.x * rb.x; v.y += ra.y * rb.y;
            v.z += ra.z * rb.z; v.w += ra.w * rb.w;
        }
        *(float4*)(y + rbase + c) = v;
    }
}

// Fused: proj = ef@e_w (per edge), val = scalar_dst[col]*proj*C[b],
// atomic scatter-add into conv[row].
__global__ __launch_bounds__(256)
void edge_kernel(const float* __restrict__ ef,    // [B,E,32]
                 const int*   __restrict__ eidx,  // [B,E,2]
                 const float* __restrict__ sdst,  // [B,N,H]
                 const float* __restrict__ ew,    // [32,H]
                 const float* __restrict__ C,     // [B]
                 float* __restrict__ conv,        // [B,N,H]
                 int E, int N)
{
    __shared__ float ews[32][H];
    __shared__ float efs[EPB][33];
    __shared__ int   rcs[EPB][2];

    const int tid = threadIdx.x;
    const int g0  = blockIdx.x * EPB;
    const int b   = g0 / E;
    const float Cb = C[b];

#pragma unroll
    for (int i = 0; i < 4; ++i) {
        int flat = tid * 4 + i * 1024;
        *(float4*)&ews[flat >> 7][flat & 127] = *(const float4*)(ew + flat);
    }
#pragma unroll
    for (int i = 0; i < 8; ++i) {
        int flat = tid + i * 256;
        efs[flat >> 5][flat & 31] = ef[(size_t)(g0 + (flat >> 5)) * 32 + (flat & 31)];
    }
    if (tid < EPB * 2) {
        rcs[tid >> 1][tid & 1] = eidx[(size_t)g0 * 2 + tid];
    }
    __syncthreads();

    const int h   = tid & 127;
    const int sub = tid >> 7;
    for (int el = sub; el < EPB; el += 2) {
        int row = rcs[el][0];
        int col = rcs[el][1];
        float proj = 0.f;
#pragma unroll
        for (int k = 0; k < 32; ++k)
            proj = fmaf(efs[el][k], ews[k][h], proj);
        float v = sdst[((size_t)b * N + col) * H + h] * proj * Cb;
        atomicAdd(&conv[((size_t)b * N + row) * H + h], v);
    }
}

extern "C" void kernel_launch(void* const* d_in, const int* in_sizes, int n_in,
                              void* d_out, int out_size, void* d_ws, size_t ws_size,
                              hipStream_t stream)
{
    const float* scalar = (const float*)d_in[0];   // [B,N,H]
    const float* ef     = (const float*)d_in[1];   // [B,E,32]
    const int*   eidx   = (const int*)d_in[2];     // [B,E,2]
    const float* C      = (const float*)d_in[3];   // [B]
    const float* emb_w  = (const float*)d_in[4];   // [2,2,H,H]
    const float* emb_b  = (const float*)d_in[5];   // [2,2,H]
    const float* e_w    = (const float*)d_in[6];   // [32,H]
    const float* conv_w = (const float*)d_in[7];   // [2,2,H,H]
    const float* conv_b = (const float*)d_in[8];   // [2,2,H]
    const float* out_w  = (const float*)d_in[9];   // [2,H,H]
    const float* out_b  = (const float*)d_in[10];  // [2,H]

    const int B = 4, N = 10000, E = 160000;
    const int M = B * N;                           // 40000
    const size_t nodeElems = (size_t)M * H;

    float* s2s  = (float*)d_ws;
    float* sdst = s2s  + nodeElems;
    float* conv = sdst + nodeElems;

    const int HH = H * H;
    dim3 blk(256);
    dim3 grid_mlp(M / TILE_M);                     // 625
    dim3 grid_edge((B * E) / EPB);                 // 10000

    hipMemsetAsync(conv, 0, nodeElems * sizeof(float), stream);

    // s2s = Dense(Dense(scalar; emb[0,0]); emb[0,1])
    mlp2_mfma<0><<<grid_mlp, blk, 0, stream>>>(
        scalar, nullptr, emb_w, emb_b, emb_w + HH, emb_b + H, s2s, M);
    // scalar_dst = Dense(Dense(scalar; emb[1,0]); emb[1,1])
    mlp2_mfma<0><<<grid_mlp, blk, 0, stream>>>(
        scalar, nullptr, emb_w + 2 * HH, emb_b + 2 * H, emb_w + 3 * HH,
        emb_b + 3 * H, sdst, M);
    // conv = segment_sum(gather(sdst,col)*ef@e_w, row) * C
    edge_kernel<<<grid_edge, blk, 0, stream>>>(ef, eidx, sdst, e_w, C, conv, E, N);
    // conv = residual(conv; conv_w[0])
    mlp2_mfma<1><<<grid_mlp, blk, 0, stream>>>(
        conv, nullptr, conv_w, conv_b, conv_w + HH, conv_b + H, conv, M);
    // conv = residual(conv; conv_w[1])
    mlp2_mfma<1><<<grid_mlp, blk, 0, stream>>>(
        conv, nullptr, conv_w + 2 * HH, conv_b + 2 * H, conv_w + 3 * HH,
        conv_b + 3 * H, conv, M);
    // out = residual(s2s .* conv; out_w)   (mul fused into staging)
    mlp2_mfma<2><<<grid_mlp, blk, 0, stream>>>(
        s2s, conv, out_w, out_b, out_w + HH, out_b + H, (float*)d_out, M);
}

// Round 3
// 451.827 us; speedup vs baseline: 1.4122x; 1.0970x over previous
//
#include <hip/hip_runtime.h>
#include <hip/hip_bf16.h>

#define H 128

typedef _Float16 f16x4 __attribute__((ext_vector_type(4)));
typedef _Float16 f16x8 __attribute__((ext_vector_type(8)));
typedef float    f32x4 __attribute__((ext_vector_type(4)));

__device__ __forceinline__ float silu_f(float v) {
    return v / (1.0f + __expf(-v));
}

// ---------------------------------------------------------------------------
// Weight pre-pack: 10 matrices [128k][128c] f32 -> fp16 A-frag layout.
// Frag for (mat, ct, kb): lane holds m = ct*16+(lane&15), k = kb*32+(lane>>4)*8+j.
// wpk element offset = (((mat*8+ct)*4+kb)*64 + lane)*8 + j   (16B per lane, contiguous)
// ---------------------------------------------------------------------------
__global__ __launch_bounds__(256)
void pack_w(const float* __restrict__ emb_w, const float* __restrict__ conv_w,
            const float* __restrict__ out_w, _Float16* __restrict__ wpk)
{
    const int gid = blockIdx.x * 256 + threadIdx.x;     // 20480 = 10*2048
    const int mat = gid >> 11;
    const int r   = gid & 2047;
    const int ct  = r >> 8;
    const int kb  = (r >> 6) & 3;
    const int lane = r & 63;
    const float* W = (mat < 4) ? emb_w + mat * 16384
                   : (mat < 8) ? conv_w + (mat - 4) * 16384
                               : out_w + (mat - 8) * 16384;
    const int m  = ct * 16 + (lane & 15);
    const int k0 = kb * 32 + (lane >> 4) * 8;
    _Float16* dst = wpk + (size_t)gid * 8;
#pragma unroll
    for (int j = 0; j < 8; ++j)
        dst[j] = (_Float16)W[(k0 + j) * H + m];
}

// ---------------------------------------------------------------------------
// Fused two-layer dense on matrix cores, sync-free:
//   MODE 0: y = mlp2(x)
//   MODE 1: y = x + mlp2(x)
//   MODE 2: z = x .* x2;  y = z + mlp2(z)
// A-frags direct from packed global weights (L1/L2 broadcast), B-frags direct
// from global x (each row read exactly once), hidden via wave-private LDS.
// ---------------------------------------------------------------------------
template <int MODE>
__global__ __launch_bounds__(256)
void mlp2_v2(const float* __restrict__ x, const float* __restrict__ x2,
             const _Float16* __restrict__ wpk,   // 2 mats (32768 halves)
             const float* __restrict__ b0, const float* __restrict__ b1,
             float* __restrict__ y)
{
    __shared__ _Float16 hs[4][16 * 136];   // per-wave hidden, 17.4 KB
    const int tid  = threadIdx.x;
    const int lane = tid & 63;
    const int wid  = tid >> 6;
    const int rl   = lane & 15;
    const int quad = lane >> 4;
    const int row  = blockIdx.x * 64 + wid * 16 + rl;
    const size_t rbase = (size_t)row * H;
    _Float16* hw = &hs[wid][0];

    f32x4 acc[8];
#pragma unroll
    for (int ct = 0; ct < 8; ++ct) acc[ct] = (f32x4){0.f, 0.f, 0.f, 0.f};

    // ---- layer 1: B from global f32 x ----
#pragma unroll
    for (int kb = 0; kb < 4; ++kb) {
        const int kc = kb * 32 + quad * 8;
        float4 v0 = *(const float4*)(x + rbase + kc);
        float4 v1 = *(const float4*)(x + rbase + kc + 4);
        if (MODE == 2) {
            float4 u0 = *(const float4*)(x2 + rbase + kc);
            float4 u1 = *(const float4*)(x2 + rbase + kc + 4);
            v0.x *= u0.x; v0.y *= u0.y; v0.z *= u0.z; v0.w *= u0.w;
            v1.x *= u1.x; v1.y *= u1.y; v1.z *= u1.z; v1.w *= u1.w;
        }
        f16x8 bf = {(_Float16)v0.x, (_Float16)v0.y, (_Float16)v0.z, (_Float16)v0.w,
                    (_Float16)v1.x, (_Float16)v1.y, (_Float16)v1.z, (_Float16)v1.w};
#pragma unroll
        for (int ct = 0; ct < 8; ++ct) {
            f16x8 af = *(const f16x8*)(wpk + ((size_t)(ct * 4 + kb) * 64 + lane) * 8);
            acc[ct] = __builtin_amdgcn_mfma_f32_16x16x32_f16(af, bf, acc[ct], 0, 0, 0);
        }
    }

    // ---- hidden = silu(acc+b0) -> wave-private LDS (no barrier needed) ----
#pragma unroll
    for (int ct = 0; ct < 8; ++ct) {
        const int c = ct * 16 + quad * 4;
        float4 bb = *(const float4*)(b0 + c);
        f16x4 hv = {(_Float16)silu_f(acc[ct][0] + bb.x),
                    (_Float16)silu_f(acc[ct][1] + bb.y),
                    (_Float16)silu_f(acc[ct][2] + bb.z),
                    (_Float16)silu_f(acc[ct][3] + bb.w)};
        *(f16x4*)(hw + rl * 136 + c) = hv;
    }

    // ---- layer 2 ----
#pragma unroll
    for (int ct = 0; ct < 8; ++ct) acc[ct] = (f32x4){0.f, 0.f, 0.f, 0.f};
#pragma unroll
    for (int kb = 0; kb < 4; ++kb) {
        f16x8 bf = *(const f16x8*)(hw + rl * 136 + kb * 32 + quad * 8);
#pragma unroll
        for (int ct = 0; ct < 8; ++ct) {
            f16x8 af = *(const f16x8*)(wpk + 16384 +
                                       ((size_t)(ct * 4 + kb) * 64 + lane) * 8);
            acc[ct] = __builtin_amdgcn_mfma_f32_16x16x32_f16(af, bf, acc[ct], 0, 0, 0);
        }
    }

    // ---- epilogue ----
#pragma unroll
    for (int ct = 0; ct < 8; ++ct) {
        const int c = ct * 16 + quad * 4;
        float4 bb = *(const float4*)(b1 + c);
        float4 v;
        v.x = silu_f(acc[ct][0] + bb.x);
        v.y = silu_f(acc[ct][1] + bb.y);
        v.z = silu_f(acc[ct][2] + bb.z);
        v.w = silu_f(acc[ct][3] + bb.w);
        if (MODE == 1) {
            float4 rv = *(const float4*)(x + rbase + c);
            v.x += rv.x; v.y += rv.y; v.z += rv.z; v.w += rv.w;
        } else if (MODE == 2) {
            float4 ra = *(const float4*)(x + rbase + c);
            float4 rb = *(const float4*)(x2 + rbase + c);
            v.x += ra.x * rb.x; v.y += ra.y * rb.y;
            v.z += ra.z * rb.z; v.w += ra.w * rb.w;
        }
        *(float4*)(y + rbase + c) = v;
    }
}

// ---------------------------------------------------------------------------
// Counting sort of edges by destination node (flat key = b*N + row)
// ---------------------------------------------------------------------------
__global__ __launch_bounds__(256)
void hist_k(const int* __restrict__ eidx, int* __restrict__ cnt)
{
    const int e = blockIdx.x * 256 + threadIdx.x;       // 640000 exact
    const int row = eidx[2 * (size_t)e];
    const int b = (unsigned)e / 160000u;
    atomicAdd(&cnt[b * 10000 + row], 1);
}

__global__ void scan_a(const int* __restrict__ cnt, int* __restrict__ psum)
{
    __shared__ int sh[1024];
    const int tid = threadIdx.x;
    sh[tid] = cnt[blockIdx.x * 1024 + tid];
    __syncthreads();
    for (int s = 512; s > 0; s >>= 1) {
        if (tid < s) sh[tid] += sh[tid + s];
        __syncthreads();
    }
    if (tid == 0) psum[blockIdx.x] = sh[0];
}

__global__ void scan_b(int* __restrict__ psum)
{
    if (threadIdx.x == 0) {
        int run = 0;
        for (int i = 0; i < 40; ++i) { int t = psum[i]; psum[i] = run; run += t; }
    }
}

__global__ void scan_c(const int* __restrict__ cnt, const int* __restrict__ psum,
                       int* __restrict__ offs, int* __restrict__ cursor)
{
    __shared__ int sh[1024];
    const int tid = threadIdx.x;
    const int i = blockIdx.x * 1024 + tid;
    const int v = cnt[i];
    sh[tid] = v;
    __syncthreads();
    for (int s = 1; s < 1024; s <<= 1) {
        int t = (tid >= s) ? sh[tid - s] : 0;
        __syncthreads();
        sh[tid] += t;
        __syncthreads();
    }
    const int excl = sh[tid] - v + psum[blockIdx.x];
    offs[i] = excl;
    cursor[i] = excl;
    if (i == 40959) offs[40960] = excl + v;
}

__global__ __launch_bounds__(256)
void scatter_k(const int* __restrict__ eidx, int* __restrict__ cursor,
               int* __restrict__ se, int* __restrict__ scol)
{
    const int e = blockIdx.x * 256 + threadIdx.x;       // 640000 exact
    const int2 rc = ((const int2*)eidx)[e];
    const int b = (unsigned)e / 160000u;
    const int pos = atomicAdd(&cursor[b * 10000 + rc.x], 1);
    se[pos] = e;
    scol[pos] = b * 10000 + rc.y;
}

// ---------------------------------------------------------------------------
// Gather-reduce: conv[n][h] = C[b] * sum_{e in edges(n)} sdst[col_e][h] *
//                              (ef[e] . ew[:,h]).  2 waves per node, lane = h.
// No atomics; one plain store per (node, h).
// ---------------------------------------------------------------------------
__global__ __launch_bounds__(256)
void conv_k(const float* __restrict__ ef, const float* __restrict__ sdst,
            const float* __restrict__ ew, const float* __restrict__ C,
            const int* __restrict__ offs, const int* __restrict__ se,
            const int* __restrict__ scol, float* __restrict__ conv)
{
    const int lane = threadIdx.x & 63;
    const int gw = blockIdx.x * 4 + (threadIdx.x >> 6);  // 0..79999
    const int nid = gw >> 1;
    const int h = (gw & 1) * 64 + lane;

    float ewr[32];
#pragma unroll
    for (int k = 0; k < 32; ++k) ewr[k] = ew[k * H + h];

    const int start = offs[nid], end = offs[nid + 1];
    float acc = 0.f;
    int en = 0, scn = 0;
    if (start < end) { en = se[start]; scn = scol[start]; }
    for (int i = start; i < end; ++i) {
        const int e  = __builtin_amdgcn_readfirstlane(en);
        const int sc = __builtin_amdgcn_readfirstlane(scn);
        if (i + 1 < end) { en = se[i + 1]; scn = scol[i + 1]; }
        const float4* efp = (const float4*)(ef + (size_t)e * 32);
        const float p = sdst[(size_t)sc * H + h];
        float proj = 0.f;
#pragma unroll
        for (int kb = 0; kb < 8; ++kb) {
            float4 q = efp[kb];
            proj = fmaf(q.x, ewr[kb * 4 + 0], proj);
            proj = fmaf(q.y, ewr[kb * 4 + 1], proj);
            proj = fmaf(q.z, ewr[kb * 4 + 2], proj);
            proj = fmaf(q.w, ewr[kb * 4 + 3], proj);
        }
        acc = fmaf(p, proj, acc);
    }
    const float Cb = C[(unsigned)nid / 10000u];
    conv[(size_t)nid * H + h] = acc * Cb;
}

// ---------------------------------------------------------------------------
extern "C" void kernel_launch(void* const* d_in, const int* in_sizes, int n_in,
                              void* d_out, int out_size, void* d_ws, size_t ws_size,
                              hipStream_t stream)
{
    const float* scalar = (const float*)d_in[0];
    const float* ef     = (const float*)d_in[1];
    const int*   eidx   = (const int*)d_in[2];
    const float* C      = (const float*)d_in[3];
    const float* emb_w  = (const float*)d_in[4];
    const float* emb_b  = (const float*)d_in[5];
    const float* e_w    = (const float*)d_in[6];
    const float* conv_w = (const float*)d_in[7];
    const float* conv_b = (const float*)d_in[8];
    const float* out_w  = (const float*)d_in[9];
    const float* out_b  = (const float*)d_in[10];

    const int M = 40000;
    const size_t nodeElems = (size_t)M * H;            // 5,120,000

    float* s2s  = (float*)d_ws;
    float* sdst = s2s + nodeElems;
    float* conv = sdst + nodeElems;
    _Float16* wpk = (_Float16*)(conv + nodeElems);     // 163840 halves (16B-aligned)
    int* cnt    = (int*)(wpk + 163840);                // 40960
    int* psum   = cnt + 40960;                         // 64
    int* offs   = psum + 64;                           // 40964
    int* cursor = offs + 40964;                        // 40960
    int* se     = cursor + 40960;                      // 640000
    int* scol   = se + 640000;                         // 640000

    const int HH = H * H;
    dim3 blk(256);

    pack_w<<<80, blk, 0, stream>>>(emb_w, conv_w, out_w, wpk);
    hipMemsetAsync(cnt, 0, 40960 * sizeof(int), stream);

    // s2s = Dense(Dense(scalar; emb[0,0]); emb[0,1])
    mlp2_v2<0><<<625, blk, 0, stream>>>(scalar, nullptr, wpk, emb_b, emb_b + H, s2s);
    // scalar_dst
    mlp2_v2<0><<<625, blk, 0, stream>>>(scalar, nullptr, wpk + 2 * HH,
                                        emb_b + 2 * H, emb_b + 3 * H, sdst);
    // counting sort of edges by destination
    hist_k<<<2500, blk, 0, stream>>>(eidx, cnt);
    scan_a<<<40, 1024, 0, stream>>>(cnt, psum);
    scan_b<<<1, 64, 0, stream>>>(psum);
    scan_c<<<40, 1024, 0, stream>>>(cnt, psum, offs, cursor);
    scatter_k<<<2500, blk, 0, stream>>>(eidx, cursor, se, scol);
    // conv = C * segment_sum(...)
    conv_k<<<20000, blk, 0, stream>>>(ef, sdst, e_w, C, offs, se, scol, conv);
    // conv = residual(conv; conv_w[0]); residual(conv; conv_w[1])
    mlp2_v2<1><<<625, blk, 0, stream>>>(conv, nullptr, wpk + 4 * HH,
                                        conv_b, conv_b + H, conv);
    mlp2_v2<1><<<625, blk, 0, stream>>>(conv, nullptr, wpk + 6 * HH,
                                        conv_b + 2 * H, conv_b + 3 * H, conv);
    // out = residual(s2s .* conv; out_w)
    mlp2_v2<2><<<625, blk, 0, stream>>>(s2s, conv, wpk + 8 * HH,
                                        out_b, out_b + H, (float*)d_out);
}